// Round 7
// baseline (304.470 us; speedup 1.0000x reference)
//
#include <hip/hip_runtime.h>
#include <hip/hip_bf16.h>

typedef __attribute__((ext_vector_type(8))) short short8;
typedef __attribute__((ext_vector_type(4))) float float4v;

#define BN     64       // nodes per bucket
#define CHUNKS 512      // edge chunks for counting sort
#define ELCAP  2304     // LDS edge slots per bucket (padded-to-16 lists; mean ~1504)
#define NBPAD  1568     // padded bucket count (NB=1563)
#define SAP    136      // smem_agg row pad (words)

__device__ __forceinline__ unsigned short f2bf(float f) {
    union { float f; unsigned u; } v; v.f = f;
    unsigned r = v.u + 0x7fffu + ((v.u >> 16) & 1u);   // round-to-nearest-even
    return (unsigned short)(r >> 16);
}
__device__ __forceinline__ float lo_bf(unsigned u) {
    union { unsigned u; float f; } v; v.u = u << 16; return v.f;
}
__device__ __forceinline__ float hi_bf(unsigned u) {
    union { unsigned u; float f; } v; v.u = u & 0xffff0000u; return v.f;
}

// ---------------- K1: fused [count | LN+ReLU(+zero row N) | W-prep] -----
__global__ __launch_bounds__(256) void fused_pre_kernel(
    const float* __restrict__ x, const float* __restrict__ gamma,
    const float* __restrict__ beta, unsigned* __restrict__ hbuf,
    const int* __restrict__ idx, int* __restrict__ counts,
    const float* __restrict__ Wl, const float* __restrict__ Wr,
    unsigned short* __restrict__ wsb, int N, int E, int NB, int LNB) {
    const int b = blockIdx.x, t = threadIdx.x;
    if (b < CHUNKS) {
        __shared__ int hist[NBPAD];
        for (int i = t; i < NB; i += 256) hist[i] = 0;
        __syncthreads();
        const int CH = (E + CHUNKS - 1) / CHUNKS;
        const int e0 = b * CH, e1 = min(E, e0 + CH);
        for (int e = e0 + t; e < e1; e += 256)
            atomicAdd(&hist[idx[E + e] >> 6], 1);
        __syncthreads();
        for (int i = t; i < NB; i += 256) counts[b * NBPAD + i] = hist[i];
    } else if (b < CHUNKS + LNB) {
        const int row = (b - CHUNKS) * 4 + (t >> 6);
        if (row > N) return;
        const int lane = t & 63;
        if (row == N) { hbuf[(size_t)N * 64 + lane] = 0; return; }  // dummy zero row
        const size_t base = (size_t)row * 128 + lane * 2;
        float2 v = *(const float2*)&x[base];
        float s = v.x + v.y;
        #pragma unroll
        for (int o = 32; o; o >>= 1) s += __shfl_xor(s, o, 64);
        const float mu = s * 0.0078125f;
        const float d0 = v.x - mu, d1 = v.y - mu;
        float ss = d0 * d0 + d1 * d1;
        #pragma unroll
        for (int o = 32; o; o >>= 1) ss += __shfl_xor(ss, o, 64);
        const float rs = rsqrtf(ss * 0.0078125f + 1e-5f);
        float2 g = *(const float2*)&gamma[lane * 2];
        float2 bb = *(const float2*)&beta[lane * 2];
        float h0 = fmaxf(fmaf(d0 * rs, g.x, bb.x), 0.f);
        float h1 = fmaxf(fmaf(d1 * rs, g.y, bb.y), 0.f);
        hbuf[(size_t)row * 64 + lane] = (unsigned)f2bf(h0) | ((unsigned)f2bf(h1) << 16);
    } else {
        const int s = (b - CHUNKS - LNB) * 256 + t;     // 0..4095
        const int tc = s >> 9, c = (s >> 6) & 7, l = s & 63;
        const int n  = tc * 16 + (l & 15);
        const int k0 = c * 32 + ((l >> 4) & 3) * 8;
        const float* w = (k0 < 128) ? (Wl + (size_t)n * 128 + k0)
                                    : (Wr + (size_t)n * 128 + (k0 - 128));
        unsigned short tmp[8];
        #pragma unroll
        for (int j = 0; j < 8; j++) tmp[j] = f2bf(w[j]);
        *(short8*)&wsb[(size_t)s * 8] = *(short8*)tmp;
    }
}

// ---------------- K2: per-bucket exclusive prefix over 512 chunks -------
__global__ __launch_bounds__(256) void bscan_kernel(
    int* __restrict__ counts, int* __restrict__ totals, int NB) {
    const int b = blockIdx.x * 4 + (threadIdx.x >> 6);
    if (b >= NB) return;
    const int lane = threadIdx.x & 63;
    int u[8];
    #pragma unroll
    for (int k = 0; k < 8; k++) u[k] = counts[(lane * 8 + k) * NBPAD + b];
    int s = 0;
    #pragma unroll
    for (int k = 0; k < 8; k++) { int v = u[k]; u[k] = s; s += v; }
    int incl = s;
    #pragma unroll
    for (int o = 1; o < 64; o <<= 1) {
        int v = __shfl_up(incl, o, 64);
        if (lane >= o) incl += v;
    }
    const int excl = incl - s;
    #pragma unroll
    for (int k = 0; k < 8; k++) counts[(lane * 8 + k) * NBPAD + b] = excl + u[k];
    if (lane == 63) totals[b] = incl;
}

// ---------------- K3: scan bucket totals -> bstart (2 vals/thread) ------
__global__ __launch_bounds__(1024) void tscan_kernel(
    const int* __restrict__ totals, int* __restrict__ bstart, int NB) {
    __shared__ int sd[1024];
    const int t = threadIdx.x;
    const int i0 = 2 * t, i1 = 2 * t + 1;
    const int v0 = (i0 < NB) ? totals[i0] : 0;
    const int v1 = (i1 < NB) ? totals[i1] : 0;
    const int pr = v0 + v1;
    sd[t] = pr;
    __syncthreads();
    for (int off = 1; off < 1024; off <<= 1) {
        int u = (t >= off) ? sd[t - off] : 0;
        __syncthreads();
        sd[t] += u;
        __syncthreads();
    }
    const int ex = sd[t] - pr;
    if (i0 <= NB) bstart[i0] = ex;
    if (i1 <= NB) bstart[i1] = ex + v0;
}

// ---------------- K4: place (dst,src) pairs into dst-bucketed ebuf ------
__global__ __launch_bounds__(256) void bucket_kernel(
    const int* __restrict__ idx, const int* __restrict__ counts,
    const int* __restrict__ bstart, int2* __restrict__ ebuf, int E, int NB) {
    __shared__ int cur[NBPAD];
    const int t = threadIdx.x, c = blockIdx.x;
    for (int i = t; i < NB; i += 256) cur[i] = bstart[i] + counts[c * NBPAD + i];
    __syncthreads();
    const int CH = (E + CHUNKS - 1) / CHUNKS;
    const int e0 = c * CH, e1 = min(E, e0 + CH);
    for (int e = e0 + t; e < e1; e += 256) {
        const int src = idx[e];
        const int dst = idx[E + e];
        const int pos = atomicAdd(&cur[dst >> 6], 1);
        ebuf[pos] = make_int2(dst, src);
    }
}

// ---------------- K5: per-bucket adjacency + burst gather + MFMA --------
// out[i][:] = mean_j h[j] @ W_l^T + b_l + h[i] @ W_r^T + x[i]
__global__ __launch_bounds__(256) void fused_out_kernel(
    float* __restrict__ out, const unsigned* __restrict__ hbuf,
    const float* __restrict__ x, const unsigned short* __restrict__ wsb,
    const float* __restrict__ bl, const int2* __restrict__ ebuf,
    const int* __restrict__ bstart, int N) {
    __shared__ int elds[ELCAP];                 // 9 KB
    __shared__ float smem_agg[16][SAP];         // 8.7 KB
    __shared__ unsigned short a_lds[8][64][8];  // 8 KB
    __shared__ int hist[BN], segstart[BN], cur2[BN];
    const int t = threadIdx.x, w = t >> 6, l = t & 63;
    const int half = l >> 5, hl = l & 31;
    const int b = blockIdx.x;
    const int nodebase = b * BN;
    const int e0 = bstart[b], cnt = bstart[b + 1] - e0;

    // ---- per-node degree histogram
    if (t < BN) hist[t] = 0;
    __syncthreads();
    for (int i = t; i < cnt; i += 256) {
        int2 p = ebuf[e0 + i];
        atomicAdd(&hist[p.x & (BN - 1)], 1);
    }
    __syncthreads();
    // ---- exclusive scan over padded (×16, min 16) degrees
    int pdv = 0;
    if (t < BN) {
        pdv = (hist[t] + 15) & ~15;
        if (pdv == 0) pdv = 16;
        cur2[t] = pdv;
    }
    __syncthreads();
    for (int off = 1; off < BN; off <<= 1) {
        int u = (t < BN && t >= off) ? cur2[t - off] : 0;
        __syncthreads();
        if (t < BN) cur2[t] += u;
        __syncthreads();
    }
    if (t < BN) { segstart[t] = cur2[t] - pdv; cur2[t] = segstart[t]; }
    __syncthreads();
    // ---- place srcs grouped by local dst
    for (int i = t; i < cnt; i += 256) {
        int2 p = ebuf[e0 + i];
        int pos = atomicAdd(&cur2[p.x & (BN - 1)], 1);
        if (pos < ELCAP) elds[pos] = p.y;
    }
    __syncthreads();
    // ---- fill pad slots with dummy zero-row index N
    if (t < BN) {
        const int pe = segstart[t] + pdv;
        for (int p = cur2[t]; p < pe; p++) if (p < ELCAP) elds[p] = N;
    }
    __syncthreads();

    // ---- 4 tiles of 16 rows
    for (int tile = 0; tile < 4; tile++) {
        // P1: burst-pipelined gather; wave w owns rows w*4..w*4+3.
        // Lists padded to x16 with zero-row dummies -> branch-free 16-edge batches.
        int nb[4], sb[4];
        #pragma unroll
        for (int i = 0; i < 4; i++) {
            const int ln = tile * 16 + w * 4 + i;
            int pd = (hist[ln] + 15) & ~15;
            if (pd == 0) pd = 16;
            sb[i] = segstart[ln];
            nb[i] = pd >> 4;
        }
        // burst: batch 0 of all 4 rows -> 32 independent loads in flight
        uint2 buf[4][8];
        #pragma unroll
        for (int i = 0; i < 4; i++) {
            #pragma unroll
            for (int k = 0; k < 8; k++) {
                const int ix = sb[i] + 2 * k + half;
                const int s = (ix < ELCAP) ? elds[ix] : N;
                buf[i][k] = *(const uint2*)(hbuf + (size_t)s * 64 + hl * 2);
            }
        }
        #pragma unroll
        for (int i = 0; i < 4; i++) {
            float a0 = 0.f, a1 = 0.f, a2 = 0.f, a3 = 0.f;
            #pragma unroll
            for (int k = 0; k < 8; k++) {
                a0 += lo_bf(buf[i][k].x); a1 += hi_bf(buf[i][k].x);
                a2 += lo_bf(buf[i][k].y); a3 += hi_bf(buf[i][k].y);
            }
            for (int bb = 1; bb < nb[i]; bb++) {        // tail (deg>16), short
                uint2 tb[8];
                #pragma unroll
                for (int k = 0; k < 8; k++) {
                    const int ix = sb[i] + 16 * bb + 2 * k + half;
                    const int s = (ix < ELCAP) ? elds[ix] : N;
                    tb[k] = *(const uint2*)(hbuf + (size_t)s * 64 + hl * 2);
                }
                #pragma unroll
                for (int k = 0; k < 8; k++) {
                    a0 += lo_bf(tb[k].x); a1 += hi_bf(tb[k].x);
                    a2 += lo_bf(tb[k].y); a3 += hi_bf(tb[k].y);
                }
            }
            // combine even/odd-edge halves; lanes 0..31 hold channels 4hl..4hl+3
            a0 += __shfl_xor(a0, 32, 64);
            a1 += __shfl_xor(a1, 32, 64);
            a2 += __shfl_xor(a2, 32, 64);
            a3 += __shfl_xor(a3, 32, 64);
            if (l < 32) {
                const int lr = w * 4 + i;
                *(float4v*)&smem_agg[lr][4 * hl] = (float4v){a0, a1, a2, a3};
            }
        }
        __syncthreads();

        // P2: stage z = [mean(128) || h(128)] into MFMA A-frag layout (R5-verified)
        {
            const int r = t >> 4, seg = t & 15;
            const int ln = tile * 16 + r;
            const int c8 = seg >> 1;
            unsigned short tmp[16];
            if (seg < 8) {
                const int dv = hist[ln];
                const float inv = (dv > 0) ? (1.f / (float)dv) : 0.f;
                const float4v* sp4 = (const float4v*)&smem_agg[r][seg * 16];
                #pragma unroll
                for (int q4 = 0; q4 < 4; q4++) {
                    float4v v = sp4[q4];
                    tmp[q4*4+0] = f2bf(v.x * inv); tmp[q4*4+1] = f2bf(v.y * inv);
                    tmp[q4*4+2] = f2bf(v.z * inv); tmp[q4*4+3] = f2bf(v.w * inv);
                }
            } else {
                int hr = nodebase + ln;
                if (hr > N) hr = N;                     // zero row for tail
                const unsigned short* hp =
                    (const unsigned short*)hbuf + (size_t)hr * 128 + (seg - 8) * 16;
                #pragma unroll
                for (int i2 = 0; i2 < 16; i2++) tmp[i2] = hp[i2];
            }
            #pragma unroll
            for (int hf = 0; hf < 2; hf++) {
                const int q = ((seg & 1) << 1) + hf;
                *(short8*)&a_lds[c8][q * 16 + r][0] = *(short8*)&tmp[hf * 8];
            }
        }
        __syncthreads();

        // P3: MFMA — wave computes 16 rows x 2 col-tiles (R5-verified)
        short8 af[8];
        #pragma unroll
        for (int c = 0; c < 8; c++) af[c] = *(const short8*)&a_lds[c][l][0];

        float4v macc[2] = {{0.f,0.f,0.f,0.f},{0.f,0.f,0.f,0.f}};
        #pragma unroll
        for (int tt = 0; tt < 2; tt++) {
            const int tc = w * 2 + tt;
            const short8* bw = (const short8*)(wsb + (size_t)tc * 8 * 64 * 8);
            #pragma unroll
            for (int c = 0; c < 8; c++) {
                short8 bf = bw[c * 64 + l];
                macc[tt] = __builtin_amdgcn_mfma_f32_16x16x32_bf16(af[c], bf, macc[tt], 0, 0, 0);
            }
        }

        // epilogue (+b_l +x); C/D layout: col=lane&15, row=quad*4+reg
        #pragma unroll
        for (int tt = 0; tt < 2; tt++) {
            const int col = (w * 2 + tt) * 16 + (l & 15);
            const float blv = bl[col];
            #pragma unroll
            for (int rr = 0; rr < 4; rr++) {
                const int row = nodebase + tile * 16 + (l >> 4) * 4 + rr;
                if (row < N)
                    out[(size_t)row * 128 + col] = macc[tt][rr] + blv + x[(size_t)row * 128 + col];
            }
        }
        __syncthreads();
    }
}

extern "C" void kernel_launch(void* const* d_in, const int* in_sizes, int n_in,
                              void* d_out, int out_size, void* d_ws, size_t ws_size,
                              hipStream_t stream) {
    const float* x     = (const float*)d_in[0];
    const int*   ei    = (const int*)d_in[1];
    const float* gamma = (const float*)d_in[2];
    const float* beta  = (const float*)d_in[3];
    const float* Wl    = (const float*)d_in[4];
    const float* bl    = (const float*)d_in[5];
    const float* Wr    = (const float*)d_in[6];
    float* out = (float*)d_out;

    const int C = 128;
    const int N = in_sizes[0] / C;          // 100000
    const int E = in_sizes[1] / 2;          // 1600000
    const int NB = (N + BN - 1) / BN;       // 1563

    char* ws = (char*)d_ws;
    size_t off = 0;
    unsigned* hbuf = (unsigned*)(ws + off);  off += (size_t)(N + 1) * 256;      // 25.6 MB (+zero row)
    int2* ebuf     = (int2*)(ws + off);      off += (size_t)E * 8;              // 12.8 MB
    int* counts    = (int*)(ws + off);       off += (size_t)CHUNKS * NBPAD * 4; // 3.2 MB
    int* totals    = (int*)(ws + off);       off += 8192;
    int* bstart    = (int*)(ws + off);       off += 8192;
    unsigned short* wsb = (unsigned short*)(ws + off);                          // 64 KB

    const int LNB = (N + 4 + 3) / 4;        // covers rows 0..N (incl. zero row)
    fused_pre_kernel<<<CHUNKS + LNB + 16, 256, 0, stream>>>(
        x, gamma, beta, hbuf, ei, counts, Wl, Wr, wsb, N, E, NB, LNB);
    bscan_kernel<<<(NB + 3) / 4, 256, 0, stream>>>(counts, totals, NB);
    tscan_kernel<<<1, 1024, 0, stream>>>(totals, bstart, NB);
    bucket_kernel<<<CHUNKS, 256, 0, stream>>>(ei, counts, bstart, ebuf, E, NB);
    fused_out_kernel<<<NB, 256, 0, stream>>>(out, hbuf, x, wsb, bl, ebuf, bstart, N);
}